// Round 1
// baseline (2569.341 us; speedup 1.0000x reference)
//
#include <hip/hip_runtime.h>
#include <hip/hip_bf16.h>
#include <cstdint>
#include <cstddef>

// CascadeAttention on MI355X — v0: correct fp32 baseline.
// Pipeline per call: bias gather; for each of 8 heads (cascade-serial):
//   qkv 1x1conv+BN -> dwconv3x3x3+BN on q -> flash attention (+rel-pos bias);
// then ReLU + proj GEMM + BN.
// Workspace use: ~72.4 MB (bias, q, qconv, k, v, cat).

#define NH    8
#define KD    16
#define DV    32
#define CH    32          // input channels per head (DIM/NH)
#define QKVO  64          // 2*KD + DV
#define DIMC  256
#define NTOK  392
#define NN    (NTOK*NTOK) // 153664
#define BSZ   128
#define EPSV  1e-5f
#define SCL   0.25f       // KEY_DIM^-0.5

// ---------------- bias gather: bias[h][n][m] = rpb[rel[n*N+m]][h] ----------
__global__ __launch_bounds__(256) void k_bias(const float* __restrict__ rpb,
                                              const int* __restrict__ rel,
                                              float* __restrict__ bias) {
  int t = blockIdx.x * 256 + threadIdx.x;
  if (t >= NH * NN) return;
  int h = t / NN;
  int pos = t - h * NN;
  bias[t] = rpb[rel[pos] * NH + h];
}

// ---------------- qkv: h = W @ feat, BN, split to q/k/v --------------------
// feat = x[:, head*32:+32] (+ cat rows of previous head's attn output).
// block 256 = 64 lanes (n) x 4 waves (o-groups of 16); W via scalar loads.
__global__ __launch_bounds__(256) void k_qkv(int head,
    const float* __restrict__ x, const float* __restrict__ cat,
    const float* __restrict__ W, const float* __restrict__ G,
    const float* __restrict__ Bp, const float* __restrict__ Mp,
    const float* __restrict__ Vp,
    float* __restrict__ qb, float* __restrict__ kb, float* __restrict__ vb) {
  int t = threadIdx.x;
  int b = blockIdx.y;
  int n = blockIdx.x * 64 + (t & 63);
  int o0 = __builtin_amdgcn_readfirstlane((t >> 6) * 16);  // wave-uniform -> s_load path
  if (n >= NTOK) return;

  const float* xp = x + ((size_t)b * DIMC + head * CH) * NTOK + n;
  float f[CH];
  if (head == 0) {
#pragma unroll
    for (int c = 0; c < CH; ++c) f[c] = xp[c * NTOK];
  } else {
    const float* cp = cat + ((size_t)b * DIMC + (head - 1) * DV) * NTOK + n;
#pragma unroll
    for (int c = 0; c < CH; ++c) f[c] = xp[c * NTOK] + cp[c * NTOK];
  }

  const float* wp = W + head * QKVO * CH;
  float acc[16];
#pragma unroll
  for (int oi = 0; oi < 16; ++oi) acc[oi] = 0.f;
#pragma unroll
  for (int c = 0; c < CH; ++c) {
    float fv = f[c];
#pragma unroll
    for (int oi = 0; oi < 16; ++oi) acc[oi] += wp[(o0 + oi) * CH + c] * fv;
  }
#pragma unroll
  for (int oi = 0; oi < 16; ++oi) {
    int o = o0 + oi;
    float g = G[head * QKVO + o], vv = Vp[head * QKVO + o];
    float s = g * rsqrtf(vv + EPSV);
    float sh = Bp[head * QKVO + o] - Mp[head * QKVO + o] * s;
    float r = acc[oi] * s + sh;
    if (o < KD)            qb[((size_t)b * KD + o) * NTOK + n] = r;
    else if (o < 2 * KD)   kb[((size_t)b * KD + (o - KD)) * NTOK + n] = r;
    else                   vb[((size_t)b * DV + (o - 2 * KD)) * NTOK + n] = r;
  }
}

// ---------------- depthwise 3x3x3 conv + BN on q ---------------------------
// one block per (channel, batch); q row staged in LDS.
__global__ __launch_bounds__(128) void k_dwconv(int head,
    const float* __restrict__ qb, const float* __restrict__ DW,
    const float* __restrict__ G, const float* __restrict__ Bp,
    const float* __restrict__ Mp, const float* __restrict__ Vp,
    float* __restrict__ qc) {
  __shared__ float qs[NTOK];
  __shared__ float wc[27];
  int c = blockIdx.x, b = blockIdx.y;
  int t = threadIdx.x;
  const float* qp = qb + ((size_t)b * KD + c) * NTOK;
  for (int i = t; i < NTOK; i += 128) qs[i] = qp[i];
  if (t < 27) wc[t] = DW[(head * KD + c) * 27 + t];
  __syncthreads();
  float g = G[head * KD + c], vv = Vp[head * KD + c];
  float s = g * rsqrtf(vv + EPSV);
  float sh = Bp[head * KD + c] - Mp[head * KD + c] * s;
  for (int n = t; n < NTOK; n += 128) {
    int z = n / 49, r = n - z * 49, y = r / 7, xx = r - y * 7;
    float a = 0.f;
#pragma unroll
    for (int dz = 0; dz < 3; ++dz) {
      int zz = z + dz - 1;
      if (zz < 0 || zz >= 8) continue;
#pragma unroll
      for (int dy = 0; dy < 3; ++dy) {
        int yy = y + dy - 1;
        if (yy < 0 || yy >= 7) continue;
#pragma unroll
        for (int dx = 0; dx < 3; ++dx) {
          int xw = xx + dx - 1;
          if (xw < 0 || xw >= 7) continue;
          a += wc[dz * 9 + dy * 3 + dx] * qs[zz * 49 + yy * 7 + xw];
        }
      }
    }
    qc[((size_t)b * KD + c) * NTOK + n] = a * s + sh;
  }
}

// ---------------- attention: flash over 7 m-tiles of 56 --------------------
// block = (batch, q-tile of 56). K[16][392], V[32][393(pad)], P[56][57(pad)]
// in dynamic LDS (92416 B). Score: wave-per-query-pair, 64-lane shuffle
// softmax reductions. PV: 4c x 4q register tile per thread (t<112).
__global__ __launch_bounds__(256) void k_attn(int head,
    const float* __restrict__ qc, const float* __restrict__ kb,
    const float* __restrict__ vb, const float* __restrict__ bias,
    float* __restrict__ cat) {
  extern __shared__ float sm[];
  float* ks  = sm;            // 16*392  = 6272
  float* vs  = ks + 6272;     // 32*393  = 12576
  float* qcs = vs + 12576;    // 16*56   = 896
  float* pt  = qcs + 896;     // 56*57   = 3192
  float* mst = pt + 3192;     // 56
  float* lst = mst + 56;      // 56
  float* cor = lst + 56;      // 56

  int t = threadIdx.x;
  int qt = blockIdx.x, b = blockIdx.y;
  int n0 = qt * 56;

  const float* kp = kb + (size_t)b * KD * NTOK;
  const float* vp = vb + (size_t)b * DV * NTOK;
  for (int i = t; i < KD * NTOK; i += 256) ks[i] = kp[i];
  for (int i = t; i < DV * NTOK; i += 256) {
    int c = i / NTOK, m = i - c * NTOK;
    vs[c * 393 + m] = vp[i];
  }
  for (int i = t; i < KD * 56; i += 256) {
    int c = i / 56, qq = i - c * 56;
    qcs[i] = qc[((size_t)b * KD + c) * NTOK + n0 + qq];
  }
  if (t < 56) { mst[t] = -1e30f; lst[t] = 0.f; }
  __syncthreads();

  int l = t & 63, wv = t >> 6;
  int cg = t & 7, qg = t >> 3;     // PV mapping (active t<112)
  int c0 = cg * 4, q0 = qg * 4;
  float acc[4][4];
#pragma unroll
  for (int i = 0; i < 4; ++i)
#pragma unroll
    for (int j = 0; j < 4; ++j) acc[i][j] = 0.f;

  for (int mt = 0; mt < 7; ++mt) {
    int m0 = mt * 56;
    // ---- score + online softmax (wave wv owns queries wv*14 .. +13) ----
    for (int j = 0; j < 14; j += 2) {
      int qa = wv * 14 + j, qbq = qa + 1;
      float sa = -1e30f, sb = -1e30f;
      if (l < 56) {
        float a0 = 0.f, a1 = 0.f;
#pragma unroll
        for (int c = 0; c < KD; ++c) {
          float kv = ks[c * NTOK + m0 + l];
          a0 += qcs[c * 56 + qa] * kv;
          a1 += qcs[c * 56 + qbq] * kv;
        }
        const float* bp = bias + ((size_t)head * NTOK + n0) * NTOK + m0 + l;
        sa = a0 * SCL + bp[(size_t)qa * NTOK];
        sb = a1 * SCL + bp[(size_t)qbq * NTOK];
      }
      float ma = sa, mb = sb;
#pragma unroll
      for (int off = 32; off > 0; off >>= 1) {
        ma = fmaxf(ma, __shfl_xor(ma, off));
        mb = fmaxf(mb, __shfl_xor(mb, off));
      }
      float moa = mst[qa], mob = mst[qbq];
      float mna = fmaxf(moa, ma), mnb = fmaxf(mob, mb);
      float ea = (l < 56) ? __expf(sa - mna) : 0.f;
      float eb = (l < 56) ? __expf(sb - mnb) : 0.f;
      float sua = ea, sub = eb;
#pragma unroll
      for (int off = 32; off > 0; off >>= 1) {
        sua += __shfl_xor(sua, off);
        sub += __shfl_xor(sub, off);
      }
      if (l == 0) {
        float ca = __expf(moa - mna), cb = __expf(mob - mnb);
        mst[qa] = mna;  lst[qa] = lst[qa] * ca + sua;  cor[qa] = ca;
        mst[qbq] = mnb; lst[qbq] = lst[qbq] * cb + sub; cor[qbq] = cb;
      }
      if (l < 56) { pt[qa * 57 + l] = ea; pt[qbq * 57 + l] = eb; }
    }
    __syncthreads();
    // ---- PV: out[c0..+3][q0..+3] over this m-tile ----
    if (t < 112) {
#pragma unroll
      for (int qi = 0; qi < 4; ++qi) {
        float cf = cor[q0 + qi];
#pragma unroll
        for (int ci = 0; ci < 4; ++ci) acc[ci][qi] *= cf;
      }
      for (int mm = 0; mm < 56; ++mm) {
        float p0 = pt[(q0 + 0) * 57 + mm], p1 = pt[(q0 + 1) * 57 + mm];
        float p2 = pt[(q0 + 2) * 57 + mm], p3 = pt[(q0 + 3) * 57 + mm];
        float v0 = vs[(c0 + 0) * 393 + m0 + mm], v1 = vs[(c0 + 1) * 393 + m0 + mm];
        float v2 = vs[(c0 + 2) * 393 + m0 + mm], v3 = vs[(c0 + 3) * 393 + m0 + mm];
        acc[0][0] += v0 * p0; acc[0][1] += v0 * p1; acc[0][2] += v0 * p2; acc[0][3] += v0 * p3;
        acc[1][0] += v1 * p0; acc[1][1] += v1 * p1; acc[1][2] += v1 * p2; acc[1][3] += v1 * p3;
        acc[2][0] += v2 * p0; acc[2][1] += v2 * p1; acc[2][2] += v2 * p2; acc[2][3] += v2 * p3;
        acc[3][0] += v3 * p0; acc[3][1] += v3 * p1; acc[3][2] += v3 * p2; acc[3][3] += v3 * p3;
      }
    }
    __syncthreads();
  }

  // normalize, stage to LDS (reuse pt as [32][57]) for coalesced store
  if (t < 112) {
#pragma unroll
    for (int ci = 0; ci < 4; ++ci)
#pragma unroll
      for (int qi = 0; qi < 4; ++qi)
        pt[(c0 + ci) * 57 + q0 + qi] = acc[ci][qi] / lst[q0 + qi];
  }
  __syncthreads();
  for (int i = t; i < DV * 56; i += 256) {
    int c = i / 56, qq = i - c * 56;
    cat[((size_t)b * DIMC + head * DV + c) * NTOK + n0 + qq] = pt[c * 57 + qq];
  }
}

// ---------------- proj: out = BN(proj_w @ relu(cat)) -----------------------
// 64o x 128n tile per block; 4o x 8n register tile per thread; b128 LDS reads.
__global__ __launch_bounds__(256) void k_proj(const float* __restrict__ cat,
    const float* __restrict__ W, const float* __restrict__ G,
    const float* __restrict__ Bp, const float* __restrict__ Mp,
    const float* __restrict__ Vp, float* __restrict__ out) {
  __shared__ float at[32 * 68];   // a^T[kk][o], padded row 68 (16B-aligned)
  __shared__ float bt[32 * 132];  // b[kk][n],  padded row 132
  int t = threadIdx.x;
  int nt = blockIdx.x, ot = blockIdx.y, b = blockIdx.z;
  int n0 = nt * 128;
  int og = t >> 4, nl = t & 15;   // o0 = og*4 ; n = n0 + {0,64} + nl*4 + ni
  float acc[4][8];
#pragma unroll
  for (int i = 0; i < 4; ++i)
#pragma unroll
    for (int j = 0; j < 8; ++j) acc[i][j] = 0.f;

  for (int k0 = 0; k0 < DIMC; k0 += 32) {
    __syncthreads();
    for (int i = t; i < 64 * 32; i += 256) {
      int r = i >> 5, cc = i & 31;
      at[cc * 68 + r] = W[(ot * 64 + r) * DIMC + k0 + cc];
    }
    for (int i = t; i < 32 * 128; i += 256) {
      int r = i >> 7, nn = i & 127;
      int n = n0 + nn;
      float v = 0.f;
      if (n < NTOK) v = fmaxf(cat[((size_t)b * DIMC + k0 + r) * NTOK + n], 0.f);
      bt[r * 132 + nn] = v;
    }
    __syncthreads();
    for (int kk = 0; kk < 32; ++kk) {
      float av[4], bv[8];
#pragma unroll
      for (int oi = 0; oi < 4; ++oi) av[oi] = at[kk * 68 + og * 4 + oi];
#pragma unroll
      for (int ni = 0; ni < 4; ++ni) {
        bv[ni]     = bt[kk * 132 + nl * 4 + ni];
        bv[4 + ni] = bt[kk * 132 + 64 + nl * 4 + ni];
      }
#pragma unroll
      for (int oi = 0; oi < 4; ++oi)
#pragma unroll
        for (int nj = 0; nj < 8; ++nj) acc[oi][nj] += av[oi] * bv[nj];
    }
  }
#pragma unroll
  for (int oi = 0; oi < 4; ++oi) {
    int o = ot * 64 + og * 4 + oi;
    float s = G[o] * rsqrtf(Vp[o] + EPSV);
    float sh = Bp[o] - Mp[o] * s;
#pragma unroll
    for (int half = 0; half < 2; ++half) {
#pragma unroll
      for (int ni = 0; ni < 4; ++ni) {
        int n = n0 + half * 64 + nl * 4 + ni;
        if (n < NTOK)
          out[((size_t)b * DIMC + o) * NTOK + n] = acc[oi][half * 4 + ni] * s + sh;
      }
    }
  }
}

// ---------------------------------------------------------------------------
extern "C" void kernel_launch(void* const* d_in, const int* in_sizes, int n_in,
                              void* d_out, int out_size, void* d_ws, size_t ws_size,
                              hipStream_t stream) {
  const float* x      = (const float*)d_in[0];
  const float* qkv_w  = (const float*)d_in[1];
  const float* qkv_g  = (const float*)d_in[2];
  const float* qkv_b  = (const float*)d_in[3];
  const float* qkv_m  = (const float*)d_in[4];
  const float* qkv_v  = (const float*)d_in[5];
  const float* dw_w   = (const float*)d_in[6];
  const float* dw_g   = (const float*)d_in[7];
  const float* dw_b   = (const float*)d_in[8];
  const float* dw_m   = (const float*)d_in[9];
  const float* dw_v   = (const float*)d_in[10];
  const float* proj_w = (const float*)d_in[11];
  const float* proj_g = (const float*)d_in[12];
  const float* proj_b = (const float*)d_in[13];
  const float* proj_m = (const float*)d_in[14];
  const float* proj_v = (const float*)d_in[15];
  const float* rpb    = (const float*)d_in[16];
  const int*   rel    = (const int*)d_in[17];
  float* out = (float*)d_out;

  // workspace layout (floats); total 18,088,448 floats = 72.4 MB
  float* wsf  = (float*)d_ws;
  float* bias = wsf;                                  // 8*392*392
  float* qb   = bias + (size_t)NH * NN;               // 128*16*392
  float* qcb  = qb   + (size_t)BSZ * KD * NTOK;       // 128*16*392
  float* kbuf = qcb  + (size_t)BSZ * KD * NTOK;       // 128*16*392
  float* vbuf = kbuf + (size_t)BSZ * KD * NTOK;       // 128*32*392
  float* cat  = vbuf + (size_t)BSZ * DV * NTOK;       // 128*256*392

  (void)hipFuncSetAttribute((const void*)k_attn,
                            hipFuncAttributeMaxDynamicSharedMemorySize, 92416);

  k_bias<<<dim3((NH * NN + 255) / 256), 256, 0, stream>>>(rpb, rel, bias);

  for (int h = 0; h < NH; ++h) {
    k_qkv<<<dim3(7, 128), 256, 0, stream>>>(h, x, cat, qkv_w, qkv_g, qkv_b,
                                            qkv_m, qkv_v, qb, kbuf, vbuf);
    k_dwconv<<<dim3(16, 128), 128, 0, stream>>>(h, qb, dw_w, dw_g, dw_b,
                                                dw_m, dw_v, qcb);
    k_attn<<<dim3(7, 128), 256, 92416, stream>>>(h, qcb, kbuf, vbuf, bias, cat);
  }

  k_proj<<<dim3(4, 4, 128), 256, 0, stream>>>(cat, proj_w, proj_g, proj_b,
                                              proj_m, proj_v, out);
}

// Round 2
// 669.010 us; speedup vs baseline: 3.8405x; 3.8405x over previous
//
#include <hip/hip_runtime.h>
#include <hip/hip_bf16.h>
#include <cstdint>
#include <cstddef>

// CascadeAttention on MI355X — v1: MFMA (bf16 hi/lo) attention.
// qkv/dwconv/proj unchanged from v0 (they were ~10% of time).

#define NH    8
#define KD    16
#define DV    32
#define CH    32
#define QKVO  64
#define DIMC  256
#define NTOK  392
#define NN    (NTOK*NTOK)
#define BSZ   128
#define EPSV  1e-5f
#define SCL   0.25f

typedef float f32x4 __attribute__((ext_vector_type(4)));
typedef short bf16x8 __attribute__((ext_vector_type(8)));
typedef unsigned int u32x4 __attribute__((ext_vector_type(4)));

__device__ inline unsigned rne_bf16_bits(float x) {
  unsigned u = __float_as_uint(x);
  return (u + 0x7fffu + ((u >> 16) & 1u)) >> 16;
}

// ---------------- bias gather ----------------------------------------------
__global__ __launch_bounds__(256) void k_bias(const float* __restrict__ rpb,
                                              const int* __restrict__ rel,
                                              float* __restrict__ bias) {
  int t = blockIdx.x * 256 + threadIdx.x;
  if (t >= NH * NN) return;
  int h = t / NN;
  int pos = t - h * NN;
  bias[t] = rpb[rel[pos] * NH + h];
}

// ---------------- qkv 1x1 conv + BN + split --------------------------------
__global__ __launch_bounds__(256) void k_qkv(int head,
    const float* __restrict__ x, const float* __restrict__ cat,
    const float* __restrict__ W, const float* __restrict__ G,
    const float* __restrict__ Bp, const float* __restrict__ Mp,
    const float* __restrict__ Vp,
    float* __restrict__ qb, float* __restrict__ kb, float* __restrict__ vb) {
  int t = threadIdx.x;
  int b = blockIdx.y;
  int n = blockIdx.x * 64 + (t & 63);
  int o0 = __builtin_amdgcn_readfirstlane((t >> 6) * 16);
  if (n >= NTOK) return;

  const float* xp = x + ((size_t)b * DIMC + head * CH) * NTOK + n;
  float f[CH];
  if (head == 0) {
#pragma unroll
    for (int c = 0; c < CH; ++c) f[c] = xp[c * NTOK];
  } else {
    const float* cp = cat + ((size_t)b * DIMC + (head - 1) * DV) * NTOK + n;
#pragma unroll
    for (int c = 0; c < CH; ++c) f[c] = xp[c * NTOK] + cp[c * NTOK];
  }

  const float* wp = W + head * QKVO * CH;
  float acc[16];
#pragma unroll
  for (int oi = 0; oi < 16; ++oi) acc[oi] = 0.f;
#pragma unroll
  for (int c = 0; c < CH; ++c) {
    float fv = f[c];
#pragma unroll
    for (int oi = 0; oi < 16; ++oi) acc[oi] += wp[(o0 + oi) * CH + c] * fv;
  }
#pragma unroll
  for (int oi = 0; oi < 16; ++oi) {
    int o = o0 + oi;
    float g = G[head * QKVO + o], vv = Vp[head * QKVO + o];
    float s = g * rsqrtf(vv + EPSV);
    float sh = Bp[head * QKVO + o] - Mp[head * QKVO + o] * s;
    float r = acc[oi] * s + sh;
    if (o < KD)            qb[((size_t)b * KD + o) * NTOK + n] = r;
    else if (o < 2 * KD)   kb[((size_t)b * KD + (o - KD)) * NTOK + n] = r;
    else                   vb[((size_t)b * DV + (o - 2 * KD)) * NTOK + n] = r;
  }
}

// ---------------- depthwise 3x3x3 conv + BN --------------------------------
__global__ __launch_bounds__(128) void k_dwconv(int head,
    const float* __restrict__ qb, const float* __restrict__ DW,
    const float* __restrict__ G, const float* __restrict__ Bp,
    const float* __restrict__ Mp, const float* __restrict__ Vp,
    float* __restrict__ qc) {
  __shared__ float qs[NTOK];
  __shared__ float wc[27];
  int c = blockIdx.x, b = blockIdx.y;
  int t = threadIdx.x;
  const float* qp = qb + ((size_t)b * KD + c) * NTOK;
  for (int i = t; i < NTOK; i += 128) qs[i] = qp[i];
  if (t < 27) wc[t] = DW[(head * KD + c) * 27 + t];
  __syncthreads();
  float g = G[head * KD + c], vv = Vp[head * KD + c];
  float s = g * rsqrtf(vv + EPSV);
  float sh = Bp[head * KD + c] - Mp[head * KD + c] * s;
  for (int n = t; n < NTOK; n += 128) {
    int z = n / 49, r = n - z * 49, y = r / 7, xx = r - y * 7;
    float a = 0.f;
#pragma unroll
    for (int dz = 0; dz < 3; ++dz) {
      int zz = z + dz - 1;
      if (zz < 0 || zz >= 8) continue;
#pragma unroll
      for (int dy = 0; dy < 3; ++dy) {
        int yy = y + dy - 1;
        if (yy < 0 || yy >= 7) continue;
#pragma unroll
        for (int dx = 0; dx < 3; ++dx) {
          int xw = xx + dx - 1;
          if (xw < 0 || xw >= 7) continue;
          a += wc[dz * 9 + dy * 3 + dx] * qs[zz * 49 + yy * 7 + xw];
        }
      }
    }
    qc[((size_t)b * KD + c) * NTOK + n] = a * s + sh;
  }
}

// ---------------- attention v1: MFMA flash ---------------------------------
// Block: 4 waves x 16 queries (64 q/block, N padded to 448). Grid (7, B).
// Per m-step of 64 keys:
//   QK^T: A=[Khi|Klo] (K-dim packed hi/lo over 16 ch), B1=[Qhi|Qhi],
//         B2=[Qlo|0] -> 2 MFMAs per 16-m subtile, near-fp32 scores.
//   softmax: per-lane over 16 scores + shfl_xor(16,32) across the 4 lanes
//         sharing a query (D-frag col = lane&15).
//   PV:   A=Vhi (32 real m per MFMA), B1=Phi, B2=Plo -> 2 MFMAs per
//         (32m-chunk, 16c-tile); P staged in per-wave LDS buffer.
// Operand k-map assumed k'=8g+j for BOTH A and B of each MFMA: correctness
// is invariant to the true hardware k-order (A/B maps are symmetric).
__global__ __launch_bounds__(256, 2) void k_attn2(int head,
    const float* __restrict__ qc, const float* __restrict__ kb,
    const float* __restrict__ vb, const float* __restrict__ bias,
    float* __restrict__ cat) {
  __shared__ __align__(16) short KhiT[64 * 24];   // [m][c], stride 24
  __shared__ __align__(16) short KloT[64 * 24];
  __shared__ __align__(16) short Vhi[32 * 72];    // [c][m], stride 72
  __shared__ __align__(16) unsigned Pbuf[4][16 * 68];  // per wave [n][m'] u32(hi|lo)

  int t = threadIdx.x;
  int qt = blockIdx.x, b = blockIdx.y;
  int w = t >> 6, l = t & 63;
  int ln = l & 15, g = l >> 4;
  int tok = qt * 64 + w * 16 + ln;      // this lane's query token (D col)
  int tokc = min(tok, NTOK - 1);

  const float* qp = qc + (size_t)b * KD * NTOK;
  const float* kp = kb + (size_t)b * KD * NTOK;
  const float* vp = vb + (size_t)b * DV * NTOK;

  // ---- Q fragments in registers (per wave) ----
  bf16x8 qB1, qB2;
  {
    int c0 = 8 * (g & 1);
#pragma unroll
    for (int j = 0; j < 8; ++j) {
      float q = qp[(size_t)(c0 + j) * NTOK + tokc] * SCL;
      unsigned u = __float_as_uint(q) & 0xffff0000u;
      float lo = q - __uint_as_float(u);
      qB1[j] = (short)(u >> 16);
      qB2[j] = (g < 2) ? (short)rne_bf16_bits(lo) : (short)0;
    }
  }

  f32x4 oacc[2];
#pragma unroll
  for (int ct = 0; ct < 2; ++ct) oacc[ct] = (f32x4){0.f, 0.f, 0.f, 0.f};
  float mrun = -INFINITY, lrun = 0.f;

  const float* bbase = bias + ((size_t)head * NTOK + tokc) * NTOK;
  unsigned* pb = &Pbuf[w][0];

  for (int mt = 0; mt < 7; ++mt) {
    int m0 = mt * 64;
    __syncthreads();
    // stage K tile -> transposed hi/lo bf16 planes
    for (int i = t; i < 16 * 64; i += 256) {
      int c = i >> 6, m = i & 63;
      float v = kp[(size_t)c * NTOK + min(m0 + m, NTOK - 1)];
      unsigned u = __float_as_uint(v) & 0xffff0000u;
      float lo = v - __uint_as_float(u);
      KhiT[m * 24 + c] = (short)(u >> 16);
      KloT[m * 24 + c] = (short)rne_bf16_bits(lo);
    }
    // stage V tile -> bf16 (RNE) plane
    for (int i = t; i < 32 * 64; i += 256) {
      int c = i >> 6, m = i & 63;
      Vhi[c * 72 + m] = (short)rne_bf16_bits(vp[(size_t)c * NTOK + min(m0 + m, NTOK - 1)]);
    }
    __syncthreads();

    // ---- QK^T: 4 m-subtiles of 16 ----
    f32x4 S[4];
#pragma unroll
    for (int ms = 0; ms < 4; ++ms) {
      const short* pl = (g < 2) ? KhiT : KloT;
      bf16x8 aK = *(const bf16x8*)&pl[(16 * ms + ln) * 24 + 8 * (g & 1)];
      f32x4 acc = (f32x4){0.f, 0.f, 0.f, 0.f};
      acc = __builtin_amdgcn_mfma_f32_16x16x32_bf16(aK, qB1, acc, 0, 0, 0);
      acc = __builtin_amdgcn_mfma_f32_16x16x32_bf16(aK, qB2, acc, 0, 0, 0);
      S[ms] = acc;
    }
    // bias + tail mask (D row m = 16*ms + 4*g + r)
#pragma unroll
    for (int ms = 0; ms < 4; ++ms) {
      int mb = m0 + 16 * ms + 4 * g;
      f32x4 bv = *(const f32x4*)&bbase[min(mb, NTOK - 4)];
#pragma unroll
      for (int r = 0; r < 4; ++r) {
        float s = S[ms][r] + bv[r];
        S[ms][r] = (mb + r < NTOK) ? s : -1e30f;
      }
    }
    // ---- online softmax ----
    float tmax = -1e30f;
#pragma unroll
    for (int ms = 0; ms < 4; ++ms)
#pragma unroll
      for (int r = 0; r < 4; ++r) tmax = fmaxf(tmax, S[ms][r]);
    tmax = fmaxf(tmax, __shfl_xor(tmax, 16));
    tmax = fmaxf(tmax, __shfl_xor(tmax, 32));
    float mnew = fmaxf(mrun, tmax);
    float corr = __expf(mrun - mnew);
    float lsum = 0.f;
    unsigned pk[4][4];
#pragma unroll
    for (int ms = 0; ms < 4; ++ms)
#pragma unroll
      for (int r = 0; r < 4; ++r) {
        float p = __expf(S[ms][r] - mnew);
        lsum += p;
        unsigned u = __float_as_uint(p) & 0xffff0000u;
        float lo = p - __uint_as_float(u);
        pk[ms][r] = (u >> 16) | (rne_bf16_bits(lo) << 16);
      }
    lsum += __shfl_xor(lsum, 16);
    lsum += __shfl_xor(lsum, 32);
    lrun = lrun * corr + lsum;
    mrun = mnew;
#pragma unroll
    for (int ct = 0; ct < 2; ++ct)
#pragma unroll
      for (int r = 0; r < 4; ++r) oacc[ct][r] *= corr;
    // stage P (u32 = Phi | Plo<<16), row n = ln, col m' = 16*ms + 4*g + r
#pragma unroll
    for (int ms = 0; ms < 4; ++ms) {
      u32x4 pv = (u32x4){pk[ms][0], pk[ms][1], pk[ms][2], pk[ms][3]};
      *(u32x4*)&pb[ln * 68 + 16 * ms + 4 * g] = pv;
    }
    // ---- PV: 2 chunks of 32 m ----
#pragma unroll
    for (int ch = 0; ch < 2; ++ch) {
      const unsigned* pr = &pb[ln * 68 + 32 * ch + 8 * g];
      u32x4 pa = *(const u32x4*)pr;
      u32x4 pc2 = *(const u32x4*)(pr + 4);
      unsigned arr[8] = {pa[0], pa[1], pa[2], pa[3], pc2[0], pc2[1], pc2[2], pc2[3]};
      bf16x8 fhi, flo;
#pragma unroll
      for (int j = 0; j < 8; ++j) {
        fhi[j] = (short)(arr[j] & 0xffffu);
        flo[j] = (short)(arr[j] >> 16);
      }
#pragma unroll
      for (int ct = 0; ct < 2; ++ct) {
        bf16x8 aV = *(const bf16x8*)&Vhi[(16 * ct + ln) * 72 + 32 * ch + 8 * g];
        oacc[ct] = __builtin_amdgcn_mfma_f32_16x16x32_bf16(aV, fhi, oacc[ct], 0, 0, 0);
        oacc[ct] = __builtin_amdgcn_mfma_f32_16x16x32_bf16(aV, flo, oacc[ct], 0, 0, 0);
      }
    }
  }

  // ---- epilogue: normalize + store (PV D: col n = ln, row c = 4g + r) ----
  if (tok < NTOK) {
    float inv = 1.f / lrun;
#pragma unroll
    for (int ct = 0; ct < 2; ++ct)
#pragma unroll
      for (int r = 0; r < 4; ++r) {
        int c = head * DV + 16 * ct + 4 * g + r;
        cat[((size_t)b * DIMC + c) * NTOK + tok] = oacc[ct][r] * inv;
      }
  }
}

// ---------------- proj GEMM + BN -------------------------------------------
__global__ __launch_bounds__(256) void k_proj(const float* __restrict__ cat,
    const float* __restrict__ W, const float* __restrict__ G,
    const float* __restrict__ Bp, const float* __restrict__ Mp,
    const float* __restrict__ Vp, float* __restrict__ out) {
  __shared__ float at[32 * 68];
  __shared__ float bt[32 * 132];
  int t = threadIdx.x;
  int nt = blockIdx.x, ot = blockIdx.y, b = blockIdx.z;
  int n0 = nt * 128;
  int og = t >> 4, nl = t & 15;
  float acc[4][8];
#pragma unroll
  for (int i = 0; i < 4; ++i)
#pragma unroll
    for (int j = 0; j < 8; ++j) acc[i][j] = 0.f;

  for (int k0 = 0; k0 < DIMC; k0 += 32) {
    __syncthreads();
    for (int i = t; i < 64 * 32; i += 256) {
      int r = i >> 5, cc = i & 31;
      at[cc * 68 + r] = W[(ot * 64 + r) * DIMC + k0 + cc];
    }
    for (int i = t; i < 32 * 128; i += 256) {
      int r = i >> 7, nn = i & 127;
      int n = n0 + nn;
      float v = 0.f;
      if (n < NTOK) v = fmaxf(cat[((size_t)b * DIMC + k0 + r) * NTOK + n], 0.f);
      bt[r * 132 + nn] = v;
    }
    __syncthreads();
    for (int kk = 0; kk < 32; ++kk) {
      float av[4], bv[8];
#pragma unroll
      for (int oi = 0; oi < 4; ++oi) av[oi] = at[kk * 68 + og * 4 + oi];
#pragma unroll
      for (int ni = 0; ni < 4; ++ni) {
        bv[ni]     = bt[kk * 132 + nl * 4 + ni];
        bv[4 + ni] = bt[kk * 132 + 64 + nl * 4 + ni];
      }
#pragma unroll
      for (int oi = 0; oi < 4; ++oi)
#pragma unroll
        for (int nj = 0; nj < 8; ++nj) acc[oi][nj] += av[oi] * bv[nj];
    }
  }
#pragma unroll
  for (int oi = 0; oi < 4; ++oi) {
    int o = ot * 64 + og * 4 + oi;
    float s = G[o] * rsqrtf(Vp[o] + EPSV);
    float sh = Bp[o] - Mp[o] * s;
#pragma unroll
    for (int half = 0; half < 2; ++half) {
#pragma unroll
      for (int ni = 0; ni < 4; ++ni) {
        int n = n0 + half * 64 + nl * 4 + ni;
        if (n < NTOK)
          out[((size_t)b * DIMC + o) * NTOK + n] = acc[oi][half * 4 + ni] * s + sh;
      }
    }
  }
}

// ---------------------------------------------------------------------------
extern "C" void kernel_launch(void* const* d_in, const int* in_sizes, int n_in,
                              void* d_out, int out_size, void* d_ws, size_t ws_size,
                              hipStream_t stream) {
  const float* x      = (const float*)d_in[0];
  const float* qkv_w  = (const float*)d_in[1];
  const float* qkv_g  = (const float*)d_in[2];
  const float* qkv_b  = (const float*)d_in[3];
  const float* qkv_m  = (const float*)d_in[4];
  const float* qkv_v  = (const float*)d_in[5];
  const float* dw_w   = (const float*)d_in[6];
  const float* dw_g   = (const float*)d_in[7];
  const float* dw_b   = (const float*)d_in[8];
  const float* dw_m   = (const float*)d_in[9];
  const float* dw_v   = (const float*)d_in[10];
  const float* proj_w = (const float*)d_in[11];
  const float* proj_g = (const float*)d_in[12];
  const float* proj_b = (const float*)d_in[13];
  const float* proj_m = (const float*)d_in[14];
  const float* proj_v = (const float*)d_in[15];
  const float* rpb    = (const float*)d_in[16];
  const int*   rel    = (const int*)d_in[17];
  float* out = (float*)d_out;

  float* wsf  = (float*)d_ws;
  float* bias = wsf;
  float* qb   = bias + (size_t)NH * NN;
  float* qcb  = qb   + (size_t)BSZ * KD * NTOK;
  float* kbuf = qcb  + (size_t)BSZ * KD * NTOK;
  float* vbuf = kbuf + (size_t)BSZ * KD * NTOK;
  float* cat  = vbuf + (size_t)BSZ * DV * NTOK;

  k_bias<<<dim3((NH * NN + 255) / 256), 256, 0, stream>>>(rpb, rel, bias);

  for (int h = 0; h < NH; ++h) {
    k_qkv<<<dim3(7, 128), 256, 0, stream>>>(h, x, cat, qkv_w, qkv_g, qkv_b,
                                            qkv_m, qkv_v, qb, kbuf, vbuf);
    k_dwconv<<<dim3(16, 128), 128, 0, stream>>>(h, qb, dw_w, dw_g, dw_b,
                                                dw_m, dw_v, qcb);
    k_attn2<<<dim3(7, 128), 256, 0, stream>>>(h, qcb, kbuf, vbuf, bias, cat);
  }

  k_proj<<<dim3(4, 4, 128), 256, 0, stream>>>(cat, proj_w, proj_g, proj_b,
                                              proj_m, proj_v, out);
}

// Round 3
// 512.012 us; speedup vs baseline: 5.0181x; 1.3066x over previous
//
#include <hip/hip_runtime.h>
#include <hip/hip_bf16.h>
#include <cstdint>
#include <cstddef>

// CascadeAttention MI355X — v2: producer-side bf16 packing, barrier-free
// MFMA attention (global->reg operands), 3-term hi/lo MFMA proj.

#define NH    8
#define KD    16
#define DV    32
#define CH    32
#define QKVO  64
#define DIMC  256
#define NTOK  392
#define NPAD  448
#define NN    (NTOK*NTOK)
#define BSZ   128
#define EPSV  1e-5f
#define SCL2  0.3606737602222409f   // 0.25 * log2(e)
#define LOG2E 1.4426950408889634f

typedef float f32x4 __attribute__((ext_vector_type(4)));
typedef short bf16x8 __attribute__((ext_vector_type(8)));
typedef unsigned int u32x4 __attribute__((ext_vector_type(4)));

__device__ inline unsigned rne_bf16_bits(float x) {
  unsigned u = __float_as_uint(x);
  return (u + 0x7fffu + ((u >> 16) & 1u)) >> 16;
}
__device__ inline unsigned pack_hilo(float v) {   // u32 = hi16 | lo16<<16
  unsigned u = __float_as_uint(v) & 0xffff0000u;
  float lo = v - __uint_as_float(u);
  return (u >> 16) | (rne_bf16_bits(lo) << 16);
}
__device__ inline float unpack_hilo(unsigned w) { // hi + lo, ~fp32 exact
  return __uint_as_float(w << 16) + __uint_as_float(w & 0xffff0000u);
}

// ---------------- bias gather (scaled by log2e for exp2 softmax) -----------
__global__ __launch_bounds__(256) void k_bias(const float* __restrict__ rpb,
                                              const int* __restrict__ rel,
                                              float* __restrict__ bias) {
  int t = blockIdx.x * 256 + threadIdx.x;
  if (t >= NH * NN) return;
  int h = t / NN;
  int pos = t - h * NN;
  bias[t] = rpb[rel[pos] * NH + h] * LOG2E;
}

// ---------------- proj weight hi/lo pre-split -------------------------------
__global__ __launch_bounds__(256) void k_wsplit(const float* __restrict__ W,
                                                short* __restrict__ Whi,
                                                short* __restrict__ Wlo) {
  int i = blockIdx.x * 256 + threadIdx.x;
  if (i >= DIMC * DIMC) return;
  float v = W[i];
  unsigned u = __float_as_uint(v) & 0xffff0000u;
  Whi[i] = (short)(u >> 16);
  Wlo[i] = (short)rne_bf16_bits(v - __uint_as_float(u));
}

// ---------------- qkv 1x1 conv + BN, emit MFMA-ready K/V --------------------
// wave0 -> q fp32 [c][n] (dwconv input); wave1 -> kT[n][16hi|16lo] packed row;
// waves2,3 -> V bf16 [c][n]. n in [392,448) stores clamped copies (masked later).
__global__ __launch_bounds__(256) void k_qkv(int head,
    const float* __restrict__ x, const unsigned* __restrict__ catW,
    const float* __restrict__ W, const float* __restrict__ G,
    const float* __restrict__ Bp, const float* __restrict__ Mp,
    const float* __restrict__ Vp,
    float* __restrict__ qb, short* __restrict__ kT, short* __restrict__ vbB) {
  int t = threadIdx.x;
  int b = blockIdx.y;
  int n = blockIdx.x * 64 + (t & 63);
  int w = t >> 6;
  int o0 = __builtin_amdgcn_readfirstlane(w * 16);
  int nc = min(n, NTOK - 1);

  const float* xp = x + ((size_t)b * DIMC + head * CH) * NTOK + nc;
  float f[CH];
  if (head == 0) {
#pragma unroll
    for (int c = 0; c < CH; ++c) f[c] = xp[(size_t)c * NTOK];
  } else {
    const unsigned* cp = catW + ((size_t)b * NTOK + nc) * DIMC + (head - 1) * DV;
#pragma unroll
    for (int c = 0; c < CH; ++c) f[c] = xp[(size_t)c * NTOK] + unpack_hilo(cp[c]);
  }

  const float* wp = W + head * QKVO * CH;
  float acc[16];
#pragma unroll
  for (int oi = 0; oi < 16; ++oi) acc[oi] = 0.f;
#pragma unroll
  for (int c = 0; c < CH; ++c) {
    float fv = f[c];
#pragma unroll
    for (int oi = 0; oi < 16; ++oi) acc[oi] += wp[(o0 + oi) * CH + c] * fv;
  }
  float r[16];
#pragma unroll
  for (int oi = 0; oi < 16; ++oi) {
    int o = o0 + oi;
    float s = G[head * QKVO + o] * rsqrtf(Vp[head * QKVO + o] + EPSV);
    float sh = Bp[head * QKVO + o] - Mp[head * QKVO + o] * s;
    r[oi] = acc[oi] * s + sh;
  }

  if (w == 0) {                       // q fp32, layout [c][n]
    if (n < NTOK) {
#pragma unroll
      for (int oi = 0; oi < 16; ++oi)
        qb[((size_t)b * KD + oi) * NTOK + n] = r[oi];
    }
  } else if (w == 1) {                // K -> packed transposed row
    unsigned hi[16], lo[16];
#pragma unroll
    for (int i = 0; i < 16; ++i) {
      unsigned u = __float_as_uint(r[i]) & 0xffff0000u;
      hi[i] = u >> 16;
      lo[i] = rne_bf16_bits(r[i] - __uint_as_float(u));
    }
    unsigned kw[16];
#pragma unroll
    for (int j = 0; j < 8; ++j) {
      kw[j]     = hi[2 * j] | (hi[2 * j + 1] << 16);
      kw[8 + j] = lo[2 * j] | (lo[2 * j + 1] << 16);
    }
    short* row = kT + ((size_t)b * NPAD + n) * 32;
#pragma unroll
    for (int p = 0; p < 4; ++p)
      *(u32x4*)&row[p * 8] = (u32x4){kw[4*p], kw[4*p+1], kw[4*p+2], kw[4*p+3]};
  } else {                            // V bf16, layout [c][n]
    int vc0 = (w - 2) * 16;
#pragma unroll
    for (int oi = 0; oi < 16; ++oi)
      vbB[((size_t)b * DV + vc0 + oi) * NPAD + n] = (short)rne_bf16_bits(r[oi]);
  }
}

// ---------------- depthwise 3x3x3 conv + BN ---------------------------------
__global__ __launch_bounds__(128) void k_dwconv(int head,
    const float* __restrict__ qb, const float* __restrict__ DW,
    const float* __restrict__ G, const float* __restrict__ Bp,
    const float* __restrict__ Mp, const float* __restrict__ Vp,
    float* __restrict__ qc) {
  __shared__ float qs[NTOK];
  __shared__ float wc[27];
  int c = blockIdx.x, b = blockIdx.y;
  int t = threadIdx.x;
  const float* qp = qb + ((size_t)b * KD + c) * NTOK;
  for (int i = t; i < NTOK; i += 128) qs[i] = qp[i];
  if (t < 27) wc[t] = DW[(head * KD + c) * 27 + t];
  __syncthreads();
  float s = G[head * KD + c] * rsqrtf(Vp[head * KD + c] + EPSV);
  float sh = Bp[head * KD + c] - Mp[head * KD + c] * s;
  for (int n = t; n < NTOK; n += 128) {
    int z = n / 49, r = n - z * 49, y = r / 7, xx = r - y * 7;
    float a = 0.f;
#pragma unroll
    for (int dz = 0; dz < 3; ++dz) {
      int zz = z + dz - 1;
      if (zz < 0 || zz >= 8) continue;
#pragma unroll
      for (int dy = 0; dy < 3; ++dy) {
        int yy = y + dy - 1;
        if (yy < 0 || yy >= 7) continue;
#pragma unroll
        for (int dx = 0; dx < 3; ++dx) {
          int xw = xx + dx - 1;
          if (xw < 0 || xw >= 7) continue;
          a += wc[dz * 9 + dy * 3 + dx] * qs[zz * 49 + yy * 7 + xw];
        }
      }
    }
    qc[((size_t)b * KD + c) * NTOK + n] = a * s + sh;
  }
}

// ---------------- attention v2: barrier-free MFMA flash ---------------------
// 4 waves x 16 queries; K/V/bias operands via direct global loads; only
// per-wave P LDS round-trip. Softmax in exp2 domain (SCL,bias pre-scaled).
__global__ __launch_bounds__(256) void k_attn3(int head,
    const float* __restrict__ qc, const short* __restrict__ kT,
    const short* __restrict__ vbB, const float* __restrict__ bias,
    unsigned* __restrict__ catW) {
  __shared__ __align__(16) unsigned Pbuf[4][16 * 68];
  int t = threadIdx.x;
  int qt = blockIdx.x, b = blockIdx.y;
  int w = t >> 6, l = t & 63;
  int ln = l & 15, g = l >> 4;
  int tok = qt * 64 + w * 16 + ln;
  int tokc = min(tok, NTOK - 1);

  bf16x8 qB1, qB2;
  {
    const float* qp = qc + (size_t)b * KD * NTOK + tokc;
    int c0 = 8 * (g & 1);
#pragma unroll
    for (int j = 0; j < 8; ++j) {
      float q = qp[(size_t)(c0 + j) * NTOK] * SCL2;
      unsigned u = __float_as_uint(q) & 0xffff0000u;
      qB1[j] = (short)(u >> 16);
      qB2[j] = (g < 2) ? (short)rne_bf16_bits(q - __uint_as_float(u)) : (short)0;
    }
  }

  const short* kbase = kT + (size_t)b * NPAD * 32;
  const short* vbase = vbB + (size_t)b * DV * NPAD;
  const float* bbase = bias + ((size_t)head * NTOK + tokc) * NTOK;
  unsigned* pb = &Pbuf[w][0];
  int koff = ((g >> 1) << 4) + ((g & 1) << 3);   // A k'=8g+j: plane|c-half

  f32x4 oacc[2];
#pragma unroll
  for (int ct = 0; ct < 2; ++ct) oacc[ct] = (f32x4){0.f, 0.f, 0.f, 0.f};
  float mrun = -1e30f, lrun = 0.f;

  for (int mt = 0; mt < 7; ++mt) {
    int m0 = mt * 64;
    // ---- QK^T ----
    f32x4 S[4];
#pragma unroll
    for (int ms = 0; ms < 4; ++ms) {
      bf16x8 aK = *(const bf16x8*)&kbase[(size_t)(m0 + 16 * ms + ln) * 32 + koff];
      f32x4 a = (f32x4){0.f, 0.f, 0.f, 0.f};
      a = __builtin_amdgcn_mfma_f32_16x16x32_bf16(aK, qB1, a, 0, 0, 0);
      a = __builtin_amdgcn_mfma_f32_16x16x32_bf16(aK, qB2, a, 0, 0, 0);
      S[ms] = a;
    }
    // ---- bias + tail mask ----
#pragma unroll
    for (int ms = 0; ms < 4; ++ms) {
      int mb = m0 + 16 * ms + 4 * g;
      f32x4 bv = *(const f32x4*)&bbase[min(mb, NTOK - 4)];
#pragma unroll
      for (int r = 0; r < 4; ++r) {
        float s = S[ms][r] + bv[r];
        S[ms][r] = (mb + r < NTOK) ? s : -1e30f;
      }
    }
    // ---- online softmax (exp2 domain) ----
    float tmax = -1e30f;
#pragma unroll
    for (int ms = 0; ms < 4; ++ms)
#pragma unroll
      for (int r = 0; r < 4; ++r) tmax = fmaxf(tmax, S[ms][r]);
    tmax = fmaxf(tmax, __shfl_xor(tmax, 16));
    tmax = fmaxf(tmax, __shfl_xor(tmax, 32));
    float mnew = fmaxf(mrun, tmax);
    float corr = __builtin_amdgcn_exp2f(mrun - mnew);
    float lsum = 0.f;
    unsigned pk[4][4];
#pragma unroll
    for (int ms = 0; ms < 4; ++ms)
#pragma unroll
      for (int r = 0; r < 4; ++r) {
        float p = __builtin_amdgcn_exp2f(S[ms][r] - mnew);
        lsum += p;
        unsigned u = __float_as_uint(p) & 0xffff0000u;
        pk[ms][r] = (u >> 16) | (rne_bf16_bits(p - __uint_as_float(u)) << 16);
      }
    lsum += __shfl_xor(lsum, 16);
    lsum += __shfl_xor(lsum, 32);
    lrun = lrun * corr + lsum;
    mrun = mnew;
#pragma unroll
    for (int ct = 0; ct < 2; ++ct)
#pragma unroll
      for (int r = 0; r < 4; ++r) oacc[ct][r] *= corr;
    // ---- P via per-wave LDS (no barrier: same-wave dependency) ----
#pragma unroll
    for (int ms = 0; ms < 4; ++ms)
      *(u32x4*)&pb[ln * 68 + 16 * ms + 4 * g] =
          (u32x4){pk[ms][0], pk[ms][1], pk[ms][2], pk[ms][3]};
    // ---- PV ----
#pragma unroll
    for (int ch = 0; ch < 2; ++ch) {
      const unsigned* pr = &pb[ln * 68 + 32 * ch + 8 * g];
      u32x4 pa = *(const u32x4*)pr;
      u32x4 pc = *(const u32x4*)(pr + 4);
      unsigned arr[8] = {pa[0], pa[1], pa[2], pa[3], pc[0], pc[1], pc[2], pc[3]};
      bf16x8 fhi, flo;
#pragma unroll
      for (int j = 0; j < 8; ++j) {
        fhi[j] = (short)(arr[j] & 0xffffu);
        flo[j] = (short)(arr[j] >> 16);
      }
#pragma unroll
      for (int ct = 0; ct < 2; ++ct) {
        bf16x8 aV = *(const bf16x8*)&vbase[(size_t)(16 * ct + ln) * NPAD + m0 + 32 * ch + 8 * g];
        oacc[ct] = __builtin_amdgcn_mfma_f32_16x16x32_bf16(aV, fhi, oacc[ct], 0, 0, 0);
        oacc[ct] = __builtin_amdgcn_mfma_f32_16x16x32_bf16(aV, flo, oacc[ct], 0, 0, 0);
      }
    }
  }

  // ---- epilogue: normalize, pack hi/lo u32, store [b][n][i] ----
  if (tok < NTOK) {
    float inv = 1.f / lrun;
#pragma unroll
    for (int ct = 0; ct < 2; ++ct) {
      u32x4 wv;
#pragma unroll
      for (int r = 0; r < 4; ++r) wv[r] = pack_hilo(oacc[ct][r] * inv);
      *(u32x4*)&catW[((size_t)b * NTOK + tok) * DIMC + head * DV + 16 * ct + 4 * g] = wv;
    }
  }
}

// ---------------- proj: 3-term hi/lo MFMA GEMM + BN -------------------------
// block (nt of 64 n, b); wave w owns o in [64w, 64w+64). relu via hi sign bit.
__global__ __launch_bounds__(256) void k_proj2(const unsigned* __restrict__ catW,
    const short* __restrict__ Whi, const short* __restrict__ Wlo,
    const float* __restrict__ G, const float* __restrict__ Bp,
    const float* __restrict__ Mp, const float* __restrict__ Vp,
    float* __restrict__ out) {
  int t = threadIdx.x;
  int nt = blockIdx.x, b = blockIdx.y;
  int w = t >> 6, l = t & 63;
  int ln = l & 15, g = l >> 4;

  f32x4 acc[4][4];
#pragma unroll
  for (int i = 0; i < 4; ++i)
#pragma unroll
    for (int j = 0; j < 4; ++j) acc[i][j] = (f32x4){0.f, 0.f, 0.f, 0.f};

  for (int c8 = 0; c8 < 8; ++c8) {
    int i0 = c8 * 32 + 8 * g;
    bf16x8 Bh[4], Bl[4];
#pragma unroll
    for (int ns = 0; ns < 4; ++ns) {
      int n = min(nt * 64 + 16 * ns + ln, NTOK - 1);
      const unsigned* xp = catW + ((size_t)b * NTOK + n) * DIMC + i0;
      u32x4 xa = *(const u32x4*)xp;
      u32x4 xb = *(const u32x4*)(xp + 4);
      unsigned arr[8] = {xa[0], xa[1], xa[2], xa[3], xb[0], xb[1], xb[2], xb[3]};
#pragma unroll
      for (int j = 0; j < 8; ++j) {
        unsigned v = (arr[j] & 0x8000u) ? 0u : arr[j];   // relu via hi sign
        Bh[ns][j] = (short)(v & 0xffffu);
        Bl[ns][j] = (short)(v >> 16);
      }
    }
#pragma unroll
    for (int ot = 0; ot < 4; ++ot) {
      size_t wo = (size_t)(64 * w + 16 * ot + ln) * DIMC + i0;
      bf16x8 ah = *(const bf16x8*)&Whi[wo];
      bf16x8 al = *(const bf16x8*)&Wlo[wo];
#pragma unroll
      for (int ns = 0; ns < 4; ++ns) {
        acc[ot][ns] = __builtin_amdgcn_mfma_f32_16x16x32_bf16(ah, Bh[ns], acc[ot][ns], 0, 0, 0);
        acc[ot][ns] = __builtin_amdgcn_mfma_f32_16x16x32_bf16(ah, Bl[ns], acc[ot][ns], 0, 0, 0);
        acc[ot][ns] = __builtin_amdgcn_mfma_f32_16x16x32_bf16(al, Bh[ns], acc[ot][ns], 0, 0, 0);
      }
    }
  }

#pragma unroll
  for (int ot = 0; ot < 4; ++ot)
#pragma unroll
    for (int r = 0; r < 4; ++r) {
      int o = 64 * w + 16 * ot + 4 * g + r;
      float s = G[o] * rsqrtf(Vp[o] + EPSV);
      float sh = Bp[o] - Mp[o] * s;
#pragma unroll
      for (int ns = 0; ns < 4; ++ns) {
        int n = nt * 64 + 16 * ns + ln;
        if (n < NTOK)
          out[((size_t)b * DIMC + o) * NTOK + n] = acc[ot][ns][r] * s + sh;
      }
    }
}

// ---------------------------------------------------------------------------
extern "C" void kernel_launch(void* const* d_in, const int* in_sizes, int n_in,
                              void* d_out, int out_size, void* d_ws, size_t ws_size,
                              hipStream_t stream) {
  const float* x      = (const float*)d_in[0];
  const float* qkv_w  = (const float*)d_in[1];
  const float* qkv_g  = (const float*)d_in[2];
  const float* qkv_b  = (const float*)d_in[3];
  const float* qkv_m  = (const float*)d_in[4];
  const float* qkv_v  = (const float*)d_in[5];
  const float* dw_w   = (const float*)d_in[6];
  const float* dw_g   = (const float*)d_in[7];
  const float* dw_b   = (const float*)d_in[8];
  const float* dw_m   = (const float*)d_in[9];
  const float* dw_v   = (const float*)d_in[10];
  const float* proj_w = (const float*)d_in[11];
  const float* proj_g = (const float*)d_in[12];
  const float* proj_b = (const float*)d_in[13];
  const float* proj_m = (const float*)d_in[14];
  const float* proj_v = (const float*)d_in[15];
  const float* rpb    = (const float*)d_in[16];
  const int*   rel    = (const int*)d_in[17];
  float* out = (float*)d_out;

  // ws layout (float units), total 17,580,544 f = 70.3 MB
  float* wsf  = (float*)d_ws;
  float*    bias = wsf;                                   // 1,229,312
  float*    qb   = bias + (size_t)NH * NN;                //   802,816
  float*    qcb  = qb   + (size_t)BSZ * KD * NTOK;        //   802,816
  short*    kT   = (short*)(qcb + (size_t)BSZ * KD * NTOK);        // 1,835,008 sh
  short*    vbB  = kT + (size_t)BSZ * NPAD * 32;                   // 1,835,008 sh
  unsigned* catW = (unsigned*)(vbB + (size_t)BSZ * DV * NPAD);     // 12,845,056 u32
  short*    Whi  = (short*)(catW + (size_t)BSZ * NTOK * DIMC);     //    65,536 sh
  short*    Wlo  = Whi + (size_t)DIMC * DIMC;                      //    65,536 sh

  k_bias<<<dim3((NH * NN + 255) / 256), 256, 0, stream>>>(rpb, rel, bias);
  k_wsplit<<<dim3((DIMC * DIMC + 255) / 256), 256, 0, stream>>>(proj_w, Whi, Wlo);

  for (int h = 0; h < NH; ++h) {
    k_qkv<<<dim3(7, 128), 256, 0, stream>>>(h, x, catW, qkv_w, qkv_g, qkv_b,
                                            qkv_m, qkv_v, qb, kT, vbB);
    k_dwconv<<<dim3(16, 128), 128, 0, stream>>>(h, qb, dw_w, dw_g, dw_b,
                                                dw_m, dw_v, qcb);
    k_attn3<<<dim3(7, 128), 256, 0, stream>>>(h, qcb, kT, vbB, bias, catW);
  }

  k_proj2<<<dim3(7, 128), 256, 0, stream>>>(catW, Whi, Wlo, proj_g, proj_b,
                                            proj_m, proj_v, out);
}